// Round 8
// baseline (504.074 us; speedup 1.0000x reference)
//
#include <hip/hip_runtime.h>
#include <hip/hip_bf16.h>

#define NN 100000
#define NE 1600000
#define F 128
#define NCLS 47

#define SCAN_B 98      // ceil(NN / 1024) for node-level scan
#define NPB 256        // nodes per bucket (d >> 8)
#define BUCKETS 391    // ceil(NN / NPB)
#define ABLK 512       // phase-A blocks
#define ACHUNK (NE / ABLK)  // 3125 edges per A-block

typedef __attribute__((ext_vector_type(8))) short short8;
typedef __attribute__((ext_vector_type(8))) unsigned short u16x8;
typedef __attribute__((ext_vector_type(4))) float f32x4;

#define MFMA16(A, B, C) __builtin_amdgcn_mfma_f32_16x16x32_bf16(A, B, C, 0, 0, 0)

__device__ __forceinline__ unsigned short b16(float f) {
    unsigned int u = __builtin_bit_cast(unsigned int, f);
    unsigned int r = u + 0x7FFFu + ((u >> 16) & 1u);  // RTN-even
    return (unsigned short)(r >> 16);
}
__device__ __forceinline__ float bflo(unsigned int u) { return __builtin_bit_cast(float, u << 16); }
__device__ __forceinline__ float bfhi(unsigned int u) { return __builtin_bit_cast(float, u & 0xFFFF0000u); }

// ---------- CSR build, phase A: bucket the edges ----------
__global__ void __launch_bounds__(256) k_bhist(const int* __restrict__ dst,
                                               int* __restrict__ bucket_cnt) {
    __shared__ int hist[BUCKETS];
    const int t = threadIdx.x;
    for (int i = t; i < BUCKETS; i += 256) hist[i] = 0;
    __syncthreads();
    const int e0 = blockIdx.x * ACHUNK;
    for (int i = t; i < ACHUNK; i += 256) atomicAdd(&hist[dst[e0 + i] >> 8], 1);
    __syncthreads();
    for (int i = t; i < BUCKETS; i += 256)
        if (hist[i]) atomicAdd(&bucket_cnt[i], hist[i]);
}

__global__ void k_bscan(const int* __restrict__ bucket_cnt, int* __restrict__ bucket_off,
                        int* __restrict__ cursor) {
    const int lane = threadIdx.x & 63;
    int run = 0;
#pragma unroll
    for (int c = 0; c < 7; c++) {
        int idx = c * 64 + lane;
        int v = (idx < BUCKETS) ? bucket_cnt[idx] : 0;
        int s = v;
#pragma unroll
        for (int off = 1; off < 64; off <<= 1) {
            int n = __shfl_up(s, off);
            if (lane >= off) s += n;
        }
        int excl = run + s - v;
        if (idx <= BUCKETS) {
            bucket_off[idx] = excl;
            cursor[idx] = excl;
        }
        run += __shfl(s, 63);
    }
}

__global__ void __launch_bounds__(256) k_bscatter(const int* __restrict__ src,
                                                  const int* __restrict__ dst,
                                                  int* __restrict__ cursor,
                                                  int2* __restrict__ ebuf) {
    __shared__ int hist[BUCKETS];
    __shared__ int base[BUCKETS];
    __shared__ int rank[BUCKETS];
    const int t = threadIdx.x;
    for (int i = t; i < BUCKETS; i += 256) {
        hist[i] = 0;
        rank[i] = 0;
    }
    __syncthreads();
    const int e0 = blockIdx.x * ACHUNK;
    for (int i = t; i < ACHUNK; i += 256) atomicAdd(&hist[dst[e0 + i] >> 8], 1);
    __syncthreads();
    for (int i = t; i < BUCKETS; i += 256) {
        int h = hist[i];
        base[i] = h ? atomicAdd(&cursor[i], h) : 0;
    }
    __syncthreads();
    for (int i = t; i < ACHUNK; i += 256) {
        int s = src[e0 + i];
        int d = dst[e0 + i];
        int b = d >> 8;
        int r = atomicAdd(&rank[b], 1);
        ebuf[base[b] + r] = make_int2(s, d);
    }
}

// ---------- CSR build, phase B: per-bucket (256 nodes) ----------
__global__ void __launch_bounds__(256) k_bdeg(const int2* __restrict__ ebuf,
                                              const int* __restrict__ bucket_off,
                                              int* __restrict__ deg) {
    __shared__ int cnt[NPB];
    const int t = threadIdx.x;
    cnt[t] = 0;
    __syncthreads();
    const int e0 = bucket_off[blockIdx.x], e1 = bucket_off[blockIdx.x + 1];
    for (int i = e0 + t; i < e1; i += 256) atomicAdd(&cnt[ebuf[i].y & 255], 1);
    __syncthreads();
    int node = (blockIdx.x << 8) + t;
    if (node < NN) deg[node] = cnt[t];
}

__global__ void __launch_bounds__(256) k_bfill(const int2* __restrict__ ebuf,
                                               const int* __restrict__ bucket_off,
                                               const int* __restrict__ row_off,
                                               int* __restrict__ col) {
    __shared__ int ro[NPB];
    __shared__ int cur[NPB];
    const int t = threadIdx.x;
    int node = (blockIdx.x << 8) + t;
    ro[t] = (node < NN) ? row_off[node] : 0;
    cur[t] = 0;
    __syncthreads();
    const int e0 = bucket_off[blockIdx.x], e1 = bucket_off[blockIdx.x + 1];
    for (int i = e0 + t; i < e1; i += 256) {
        int2 e = ebuf[i];
        int d = e.y & 255;
        int p = atomicAdd(&cur[d], 1);
        col[ro[d] + p] = e.x;
    }
}

// ---------- node-level scan (row_off, inv_deg) ----------
__global__ void __launch_bounds__(256) k_part(const int* __restrict__ deg,
                                              int* __restrict__ partials) {
    __shared__ int ws[4];
    const int t = threadIdx.x, lane = t & 63, wid = t >> 6;
    int i0 = blockIdx.x * 1024 + t * 4;
    int s = 0;
    if (i0 + 3 < NN) {
        int4 v = *(const int4*)&deg[i0];
        s = v.x + v.y + v.z + v.w;
    } else {
#pragma unroll
        for (int j = 0; j < 4; j++) {
            int idx = i0 + j;
            if (idx < NN) s += deg[idx];
        }
    }
#pragma unroll
    for (int off = 1; off < 64; off <<= 1) s += __shfl_xor(s, off);
    if (lane == 0) ws[wid] = s;
    __syncthreads();
    if (t == 0) partials[blockIdx.x] = ws[0] + ws[1] + ws[2] + ws[3];
}

__global__ void k_scanpart(int* __restrict__ partials, int* __restrict__ row_off) {
    const int lane = threadIdx.x & 63;
    int v0 = (lane < SCAN_B) ? partials[lane] : 0;
    int i1 = lane + 64;
    int v1 = (i1 < SCAN_B) ? partials[i1] : 0;
    int s0 = v0;
#pragma unroll
    for (int off = 1; off < 64; off <<= 1) {
        int n = __shfl_up(s0, off);
        if (lane >= off) s0 += n;
    }
    int tot0 = __shfl(s0, 63);
    int s1 = v1;
#pragma unroll
    for (int off = 1; off < 64; off <<= 1) {
        int n = __shfl_up(s1, off);
        if (lane >= off) s1 += n;
    }
    if (lane < SCAN_B) partials[lane] = s0 - v0;
    if (i1 < SCAN_B) partials[i1] = tot0 + s1 - v1;
    if (lane == 0) row_off[NN] = NE;
}

__global__ void __launch_bounds__(256) k_offsets(const int* __restrict__ deg,
                                                 const int* __restrict__ partials,
                                                 int* __restrict__ row_off,
                                                 float* __restrict__ inv_deg) {
    __shared__ int wsum[4];
    const int t = threadIdx.x, lane = t & 63, wid = t >> 6;
    int i0 = blockIdx.x * 1024 + t * 4;
    int v[4];
    int loc = 0;
#pragma unroll
    for (int j = 0; j < 4; j++) {
        int idx = i0 + j;
        v[j] = (idx < NN) ? deg[idx] : 0;
        loc += v[j];
    }
    int run = loc;
#pragma unroll
    for (int off = 1; off < 64; off <<= 1) {
        int n = __shfl_up(run, off);
        if (lane >= off) run += n;
    }
    if (lane == 63) wsum[wid] = run;
    __syncthreads();
    int woff = partials[blockIdx.x];
#pragma unroll
    for (int wv = 0; wv < 4; wv++)
        if (wv < wid) woff += wsum[wv];
    int excl = woff + run - loc;
#pragma unroll
    for (int j = 0; j < 4; j++) {
        int idx = i0 + j;
        if (idx < NN) {
            row_off[idx] = excl;
            inv_deg[idx] = 1.0f / fmaxf((float)v[j], 1.0f);
            excl += v[j];
        }
    }
}

// ---------- fp32 -> bf16 convert (x) ----------
__global__ void k_cvt(const float* __restrict__ x, unsigned short* __restrict__ xb) {
    int t = blockIdx.x * blockDim.x + threadIdx.x;
    if (t >= NN * F / 8) return;
    const float4* x4 = (const float4*)x;
    float4 a = x4[t * 2], b = x4[t * 2 + 1];
    u16x8 o;
    o[0] = b16(a.x); o[1] = b16(a.y); o[2] = b16(a.z); o[3] = b16(a.w);
    o[4] = b16(b.x); o[5] = b16(b.y); o[6] = b16(b.z); o[7] = b16(b.w);
    ((u16x8*)xb)[t] = o;
}

// ---------- pack weights into MFMA-fragment-linear bf16 ----------
__global__ void k_pack_all(const float* __restrict__ Ws0, const float* __restrict__ Wn0,
                           const float* __restrict__ Ws1, const float* __restrict__ Wn1,
                           const float* __restrict__ Ws2, const float* __restrict__ Wn2,
                           unsigned short* __restrict__ wp) {
    int idx = blockIdx.x * blockDim.x + threadIdx.x;
    if (idx >= 77824) return;
    const float* W;
    int base, ncols;
    if (idx < 65536) {
        int m = idx >> 14;
        W = (m == 0) ? Ws0 : (m == 1) ? Wn0 : (m == 2) ? Ws1 : Wn1;
        base = m << 14;
        ncols = 128;
    } else {
        int m = (idx - 65536) / 6144;
        W = m ? Wn2 : Ws2;
        base = 65536 + m * 6144;
        ncols = NCLS;
    }
    int li = idx - base;
    int nt = li >> 11;
    int r = li & 2047;
    int kk = r >> 9;
    int r2 = r & 511;
    int lane = r2 >> 3;
    int j = r2 & 7;
    int k = kk * 32 + ((lane >> 4) << 3) + j;
    int n = nt * 16 + (lane & 15);
    float v = (n < ncols) ? W[k * ncols + n] : 0.f;
    wp[idx] = b16(v);
}

// ---------- mean aggregation: 2 nodes/wave, 16-deep gather pipeline/node ----------
__global__ void __launch_bounds__(256) k_aggb(const unsigned int* __restrict__ hb32,
                                              const int* __restrict__ row_off,
                                              const int* __restrict__ col,
                                              const float* __restrict__ inv_deg,
                                              unsigned int* __restrict__ ab32) {
    int w = (blockIdx.x * blockDim.x + threadIdx.x) >> 6;
    int lane = threadIdx.x & 63;
    int n0 = w * 2;
    if (n0 >= NN) return;
    bool has1 = (n0 + 1) < NN;
    int b0 = row_off[n0], e0 = row_off[n0 + 1];
    int b1 = has1 ? e0 : 0;
    int e1 = has1 ? row_off[n0 + 2] : 0;
    int d0 = e0 - b0, d1 = e1 - b1;
    float ax0 = 0.f, ay0 = 0.f, ax1 = 0.f, ay1 = 0.f;
    const unsigned int* hp = hb32 + lane;
    int dmax = max(d0, d1);
    for (int base = 0; base < dmax; base += 64) {
        int c0 = min(d0 - base, 64);  // may be <= 0
        int c1 = min(d1 - base, 64);
        int myc0 = (c0 > 0) ? col[b0 + base + min(lane, c0 - 1)] : 0;
        int myc1 = (c1 > 0) ? col[b1 + base + min(lane, c1 - 1)] : 0;
        int cm = max(c0, c1);
        for (int jj = 0; jj < cm; jj += 16) {
            unsigned int us0[16], us1[16];
#pragma unroll
            for (int k = 0; k < 16; k++) {
                if (jj + k < c0) {  // wave-uniform
                    int c = __shfl(myc0, jj + k);
                    us0[k] = hp[(unsigned)c * 64u];
                }
            }
#pragma unroll
            for (int k = 0; k < 16; k++) {
                if (jj + k < c1) {
                    int c = __shfl(myc1, jj + k);
                    us1[k] = hp[(unsigned)c * 64u];
                }
            }
#pragma unroll
            for (int k = 0; k < 16; k++) {
                if (jj + k < c0) {
                    ax0 += bflo(us0[k]);
                    ay0 += bfhi(us0[k]);
                }
                if (jj + k < c1) {
                    ax1 += bflo(us1[k]);
                    ay1 += bfhi(us1[k]);
                }
            }
        }
    }
    float s0 = inv_deg[n0];
    ab32[(size_t)n0 * 64 + lane] =
        (unsigned int)b16(ax0 * s0) | ((unsigned int)b16(ay0 * s0) << 16);
    if (has1) {
        float s1 = inv_deg[n0 + 1];
        ab32[(size_t)(n0 + 1) * 64 + lane] =
            (unsigned int)b16(ax1 * s1) | ((unsigned int)b16(ay1 * s1) << 16);
    }
}

// ---------- fused dual-GEMM layer via MFMA ----------
template <bool RELU>
__global__ void __launch_bounds__(256) k_layer(const unsigned short* __restrict__ hb,
                                               const unsigned short* __restrict__ ab,
                                               const unsigned short* __restrict__ wps,
                                               const unsigned short* __restrict__ wpn,
                                               const float* __restrict__ bias,
                                               unsigned short* __restrict__ outb) {
    const int wid = threadIdx.x >> 6, lane = threadIdx.x & 63;
    const int tile0 = blockIdx.x * 64;
    const short8* ws8 = (const short8*)wps;
    const short8* wn8 = (const short8*)wpn;
    short8 wf[2][2][4];
#pragma unroll
    for (int t = 0; t < 2; t++) {
        int nt = 2 * wid + t;
#pragma unroll
        for (int kk = 0; kk < 4; kk++) {
            wf[0][t][kk] = ws8[(nt * 4 + kk) * 64 + lane];
            wf[1][t][kk] = wn8[(nt * 4 + kk) * 64 + lane];
        }
    }
    const int rb = lane & 15, kq = lane >> 4;
    float bv[2];
#pragma unroll
    for (int t = 0; t < 2; t++) bv[t] = bias[(2 * wid + t) * 16 + rb];
    const short8* h8 = (const short8*)hb;
    const short8* a8 = (const short8*)ab;
    f32x4 zero = {0.f, 0.f, 0.f, 0.f};
    f32x4 acc[4][2];
#pragma unroll
    for (int m = 0; m < 4; m++)
#pragma unroll
        for (int t = 0; t < 2; t++) acc[m][t] = zero;
#pragma unroll
    for (int kk = 0; kk < 4; kk++) {
#pragma unroll
        for (int m = 0; m < 4; m++) {
            int row = tile0 + m * 16 + rb;
            int rc = row < NN ? row : NN - 1;
            int idx = rc * 16 + kk * 4 + kq;
            short8 af = h8[idx];
            short8 gf = a8[idx];
            acc[m][0] = MFMA16(af, wf[0][0][kk], acc[m][0]);
            acc[m][1] = MFMA16(af, wf[0][1][kk], acc[m][1]);
            acc[m][0] = MFMA16(gf, wf[1][0][kk], acc[m][0]);
            acc[m][1] = MFMA16(gf, wf[1][1][kk], acc[m][1]);
        }
    }
#pragma unroll
    for (int m = 0; m < 4; m++) {
#pragma unroll
        for (int reg = 0; reg < 4; reg++) {
            int row = tile0 + m * 16 + kq * 4 + reg;
            if (row < NN) {
#pragma unroll
                for (int t = 0; t < 2; t++) {
                    float v = acc[m][t][reg] + bv[t];
                    if (RELU) v = fmaxf(v, 0.f);
                    outb[(size_t)row * F + (2 * wid + t) * 16 + rb] = b16(v);
                }
            }
        }
    }
}

// ---------- final layer: MFMA (N=48) + log_softmax, fp32 out ----------
__global__ void __launch_bounds__(512) k_out(const unsigned short* __restrict__ hb,
                                             const unsigned short* __restrict__ ab,
                                             const unsigned short* __restrict__ wps,
                                             const unsigned short* __restrict__ wpn,
                                             const float* __restrict__ bias,
                                             float* __restrict__ out) {
    const int wid = threadIdx.x >> 6, lane = threadIdx.x & 63;
    const int R0 = blockIdx.x * 128 + wid * 16;
    const short8* ws8 = (const short8*)wps;
    const short8* wn8 = (const short8*)wpn;
    short8 wf[2][3][4];
#pragma unroll
    for (int nt = 0; nt < 3; nt++)
#pragma unroll
        for (int kk = 0; kk < 4; kk++) {
            wf[0][nt][kk] = ws8[(nt * 4 + kk) * 64 + lane];
            wf[1][nt][kk] = wn8[(nt * 4 + kk) * 64 + lane];
        }
    const int rb = lane & 15, kq = lane >> 4;
    float bv[3];
    bool valid[3];
#pragma unroll
    for (int nt = 0; nt < 3; nt++) {
        int c = nt * 16 + rb;
        valid[nt] = c < NCLS;
        bv[nt] = valid[nt] ? bias[c] : 0.f;
    }
    const short8* h8 = (const short8*)hb;
    const short8* a8 = (const short8*)ab;
    f32x4 zero = {0.f, 0.f, 0.f, 0.f};
    f32x4 acc[3] = {zero, zero, zero};
    int rowr = R0 + rb;
    int rc = rowr < NN ? rowr : NN - 1;
#pragma unroll
    for (int kk = 0; kk < 4; kk++) {
        int idx = rc * 16 + kk * 4 + kq;
        short8 af = h8[idx];
        short8 gf = a8[idx];
#pragma unroll
        for (int nt = 0; nt < 3; nt++) {
            acc[nt] = MFMA16(af, wf[0][nt][kk], acc[nt]);
            acc[nt] = MFMA16(gf, wf[1][nt][kk], acc[nt]);
        }
    }
#pragma unroll
    for (int reg = 0; reg < 4; reg++) {
        int row = R0 + kq * 4 + reg;
        float v[3];
        float mx = -1e30f;
#pragma unroll
        for (int nt = 0; nt < 3; nt++) {
            v[nt] = acc[nt][reg] + bv[nt];
            if (valid[nt]) mx = fmaxf(mx, v[nt]);
        }
        for (int off = 1; off < 16; off <<= 1) mx = fmaxf(mx, __shfl_xor(mx, off));
        float s = 0.f;
#pragma unroll
        for (int nt = 0; nt < 3; nt++)
            if (valid[nt]) s += expf(v[nt] - mx);
        for (int off = 1; off < 16; off <<= 1) s += __shfl_xor(s, off);
        float L = mx + logf(s);
        if (row < NN) {
#pragma unroll
            for (int nt = 0; nt < 3; nt++)
                if (valid[nt]) out[(size_t)row * NCLS + nt * 16 + rb] = v[nt] - L;
        }
    }
}

extern "C" void kernel_launch(void* const* d_in, const int* in_sizes, int n_in,
                              void* d_out, int out_size, void* d_ws, size_t ws_size,
                              hipStream_t stream) {
    (void)in_sizes; (void)n_in; (void)out_size; (void)ws_size;
    const float* x = (const float*)d_in[0];
    const int* src = (const int*)d_in[1];
    const int* dst = (const int*)d_in[2];
    const float* Ws0 = (const float*)d_in[3];
    const float* Wn0 = (const float*)d_in[4];
    const float* b0 = (const float*)d_in[5];
    const float* Ws1 = (const float*)d_in[6];
    const float* Wn1 = (const float*)d_in[7];
    const float* b1 = (const float*)d_in[8];
    const float* Ws2 = (const float*)d_in[9];
    const float* Wn2 = (const float*)d_in[10];
    const float* b2 = (const float*)d_in[11];
    float* out = (float*)d_out;

    char* w = (char*)d_ws;
    size_t off = 0;
    auto alloc = [&](size_t bytes) -> char* {
        char* p = w + off;
        off = (off + bytes + 255) & ~(size_t)255;
        return p;
    };
    int* deg = (int*)alloc((size_t)NN * 4);
    int* row_off = (int*)alloc((size_t)(NN + 1) * 4);
    int* col = (int*)alloc((size_t)NE * 4);
    float* inv_deg = (float*)alloc((size_t)NN * 4);
    int* partials = (int*)alloc((size_t)SCAN_B * 4);
    int* bucket_cnt = (int*)alloc((size_t)(BUCKETS + 1) * 4);
    int* bucket_off = (int*)alloc((size_t)(BUCKETS + 1) * 4);
    int* bcursor = (int*)alloc((size_t)(BUCKETS + 1) * 4);
    int2* ebuf = (int2*)alloc((size_t)NE * 8);
    unsigned short* xb = (unsigned short*)alloc((size_t)NN * F * 2);
    unsigned short* aggb = (unsigned short*)alloc((size_t)NN * F * 2);
    unsigned short* h1b = (unsigned short*)alloc((size_t)NN * F * 2);
    unsigned short* h2b = (unsigned short*)alloc((size_t)NN * F * 2);
    unsigned short* wp = (unsigned short*)alloc((size_t)77824 * 2);

    hipMemsetAsync(bucket_cnt, 0, (size_t)(BUCKETS + 1) * 4, stream);

    // CSR build: bucket edges, then per-bucket deg/fill
    k_bhist<<<ABLK, 256, 0, stream>>>(dst, bucket_cnt);
    k_bscan<<<1, 64, 0, stream>>>(bucket_cnt, bucket_off, bcursor);
    k_bscatter<<<ABLK, 256, 0, stream>>>(src, dst, bcursor, ebuf);
    k_bdeg<<<BUCKETS, 256, 0, stream>>>(ebuf, bucket_off, deg);
    k_part<<<SCAN_B, 256, 0, stream>>>(deg, partials);
    k_scanpart<<<1, 64, 0, stream>>>(partials, row_off);
    k_offsets<<<SCAN_B, 256, 0, stream>>>(deg, partials, row_off, inv_deg);
    k_bfill<<<BUCKETS, 256, 0, stream>>>(ebuf, bucket_off, row_off, col);

    k_cvt<<<(NN * F / 8 + 255) / 256, 256, 0, stream>>>(x, xb);
    k_pack_all<<<(77824 + 255) / 256, 256, 0, stream>>>(Ws0, Wn0, Ws1, Wn1, Ws2, Wn2, wp);

    unsigned short* wS0 = wp;
    unsigned short* wN0 = wp + 16384;
    unsigned short* wS1 = wp + 32768;
    unsigned short* wN1 = wp + 49152;
    unsigned short* wS2 = wp + 65536;
    unsigned short* wN2 = wp + 71680;

    const int AGG_B = (NN / 2 * 64 + 255) / 256;  // 12500 (2 nodes per wave)
    const int LYR_B = (NN + 63) / 64;             // 1563
    const int OUT_B = (NN + 127) / 128;           // 782

    // layer 0
    k_aggb<<<AGG_B, 256, 0, stream>>>((const unsigned int*)xb, row_off, col, inv_deg,
                                      (unsigned int*)aggb);
    k_layer<true><<<LYR_B, 256, 0, stream>>>(xb, aggb, wS0, wN0, b0, h1b);
    // layer 1
    k_aggb<<<AGG_B, 256, 0, stream>>>((const unsigned int*)h1b, row_off, col, inv_deg,
                                      (unsigned int*)aggb);
    k_layer<true><<<LYR_B, 256, 0, stream>>>(h1b, aggb, wS1, wN1, b1, h2b);
    // layer 2
    k_aggb<<<AGG_B, 256, 0, stream>>>((const unsigned int*)h2b, row_off, col, inv_deg,
                                      (unsigned int*)aggb);
    k_out<<<OUT_B, 512, 0, stream>>>(h2b, aggb, wS2, wN2, b2, out);
}

// Round 9
// 355.174 us; speedup vs baseline: 1.4192x; 1.4192x over previous
//
#include <hip/hip_runtime.h>
#include <hip/hip_bf16.h>

#define NN 100000
#define NE 1600000
#define F 128
#define NCLS 47

#define SCAN_B 98      // ceil(NN / 1024) for node-level scan
#define NPB 256        // nodes per bucket (d >> 8)
#define BUCKETS 391    // ceil(NN / NPB)
#define ABLK 512       // phase-A blocks
#define ACHUNK (NE / ABLK)  // 3125 edges per A-block

typedef __attribute__((ext_vector_type(8))) short short8;
typedef __attribute__((ext_vector_type(8))) unsigned short u16x8;
typedef __attribute__((ext_vector_type(4))) float f32x4;

#define MFMA16(A, B, C) __builtin_amdgcn_mfma_f32_16x16x32_bf16(A, B, C, 0, 0, 0)

__device__ __forceinline__ unsigned short b16(float f) {
    unsigned int u = __builtin_bit_cast(unsigned int, f);
    unsigned int r = u + 0x7FFFu + ((u >> 16) & 1u);  // RTN-even
    return (unsigned short)(r >> 16);
}
__device__ __forceinline__ float bflo(unsigned int u) { return __builtin_bit_cast(float, u << 16); }
__device__ __forceinline__ float bfhi(unsigned int u) { return __builtin_bit_cast(float, u & 0xFFFF0000u); }

// ---------- CSR build, phase A: bucket the edges ----------
__global__ void __launch_bounds__(256) k_bhist(const int* __restrict__ dst,
                                               int* __restrict__ bucket_cnt) {
    __shared__ int hist[BUCKETS];
    const int t = threadIdx.x;
    for (int i = t; i < BUCKETS; i += 256) hist[i] = 0;
    __syncthreads();
    const int e0 = blockIdx.x * ACHUNK;
    for (int i = t; i < ACHUNK; i += 256) atomicAdd(&hist[dst[e0 + i] >> 8], 1);
    __syncthreads();
    for (int i = t; i < BUCKETS; i += 256)
        if (hist[i]) atomicAdd(&bucket_cnt[i], hist[i]);
}

__global__ void k_bscan(const int* __restrict__ bucket_cnt, int* __restrict__ bucket_off,
                        int* __restrict__ cursor) {
    const int lane = threadIdx.x & 63;
    int run = 0;
#pragma unroll
    for (int c = 0; c < 7; c++) {
        int idx = c * 64 + lane;
        int v = (idx < BUCKETS) ? bucket_cnt[idx] : 0;
        int s = v;
#pragma unroll
        for (int off = 1; off < 64; off <<= 1) {
            int n = __shfl_up(s, off);
            if (lane >= off) s += n;
        }
        int excl = run + s - v;
        if (idx <= BUCKETS) {
            bucket_off[idx] = excl;
            cursor[idx] = excl;
        }
        run += __shfl(s, 63);
    }
}

__global__ void __launch_bounds__(256) k_bscatter(const int* __restrict__ src,
                                                  const int* __restrict__ dst,
                                                  int* __restrict__ cursor,
                                                  int2* __restrict__ ebuf) {
    __shared__ int hist[BUCKETS];
    __shared__ int base[BUCKETS];
    __shared__ int rank[BUCKETS];
    const int t = threadIdx.x;
    for (int i = t; i < BUCKETS; i += 256) {
        hist[i] = 0;
        rank[i] = 0;
    }
    __syncthreads();
    const int e0 = blockIdx.x * ACHUNK;
    for (int i = t; i < ACHUNK; i += 256) atomicAdd(&hist[dst[e0 + i] >> 8], 1);
    __syncthreads();
    for (int i = t; i < BUCKETS; i += 256) {
        int h = hist[i];
        base[i] = h ? atomicAdd(&cursor[i], h) : 0;
    }
    __syncthreads();
    for (int i = t; i < ACHUNK; i += 256) {
        int s = src[e0 + i];
        int d = dst[e0 + i];
        int b = d >> 8;
        int r = atomicAdd(&rank[b], 1);
        ebuf[base[b] + r] = make_int2(s, d);
    }
}

// ---------- CSR build, phase B: per-bucket (256 nodes) ----------
__global__ void __launch_bounds__(256) k_bdeg(const int2* __restrict__ ebuf,
                                              const int* __restrict__ bucket_off,
                                              int* __restrict__ deg) {
    __shared__ int cnt[NPB];
    const int t = threadIdx.x;
    cnt[t] = 0;
    __syncthreads();
    const int e0 = bucket_off[blockIdx.x], e1 = bucket_off[blockIdx.x + 1];
    for (int i = e0 + t; i < e1; i += 256) atomicAdd(&cnt[ebuf[i].y & 255], 1);
    __syncthreads();
    int node = (blockIdx.x << 8) + t;
    if (node < NN) deg[node] = cnt[t];
}

__global__ void __launch_bounds__(256) k_bfill(const int2* __restrict__ ebuf,
                                               const int* __restrict__ bucket_off,
                                               const int* __restrict__ row_off,
                                               int* __restrict__ col) {
    __shared__ int ro[NPB];
    __shared__ int cur[NPB];
    const int t = threadIdx.x;
    int node = (blockIdx.x << 8) + t;
    ro[t] = (node < NN) ? row_off[node] : 0;
    cur[t] = 0;
    __syncthreads();
    const int e0 = bucket_off[blockIdx.x], e1 = bucket_off[blockIdx.x + 1];
    for (int i = e0 + t; i < e1; i += 256) {
        int2 e = ebuf[i];
        int d = e.y & 255;
        int p = atomicAdd(&cur[d], 1);
        col[ro[d] + p] = e.x;
    }
}

// ---------- node-level scan (row_off, inv_deg) ----------
__global__ void __launch_bounds__(256) k_part(const int* __restrict__ deg,
                                              int* __restrict__ partials) {
    __shared__ int ws[4];
    const int t = threadIdx.x, lane = t & 63, wid = t >> 6;
    int i0 = blockIdx.x * 1024 + t * 4;
    int s = 0;
    if (i0 + 3 < NN) {
        int4 v = *(const int4*)&deg[i0];
        s = v.x + v.y + v.z + v.w;
    } else {
#pragma unroll
        for (int j = 0; j < 4; j++) {
            int idx = i0 + j;
            if (idx < NN) s += deg[idx];
        }
    }
#pragma unroll
    for (int off = 1; off < 64; off <<= 1) s += __shfl_xor(s, off);
    if (lane == 0) ws[wid] = s;
    __syncthreads();
    if (t == 0) partials[blockIdx.x] = ws[0] + ws[1] + ws[2] + ws[3];
}

__global__ void k_scanpart(int* __restrict__ partials, int* __restrict__ row_off) {
    const int lane = threadIdx.x & 63;
    int v0 = (lane < SCAN_B) ? partials[lane] : 0;
    int i1 = lane + 64;
    int v1 = (i1 < SCAN_B) ? partials[i1] : 0;
    int s0 = v0;
#pragma unroll
    for (int off = 1; off < 64; off <<= 1) {
        int n = __shfl_up(s0, off);
        if (lane >= off) s0 += n;
    }
    int tot0 = __shfl(s0, 63);
    int s1 = v1;
#pragma unroll
    for (int off = 1; off < 64; off <<= 1) {
        int n = __shfl_up(s1, off);
        if (lane >= off) s1 += n;
    }
    if (lane < SCAN_B) partials[lane] = s0 - v0;
    if (i1 < SCAN_B) partials[i1] = tot0 + s1 - v1;
    if (lane == 0) row_off[NN] = NE;
}

__global__ void __launch_bounds__(256) k_offsets(const int* __restrict__ deg,
                                                 const int* __restrict__ partials,
                                                 int* __restrict__ row_off,
                                                 float* __restrict__ inv_deg) {
    __shared__ int wsum[4];
    const int t = threadIdx.x, lane = t & 63, wid = t >> 6;
    int i0 = blockIdx.x * 1024 + t * 4;
    int v[4];
    int loc = 0;
#pragma unroll
    for (int j = 0; j < 4; j++) {
        int idx = i0 + j;
        v[j] = (idx < NN) ? deg[idx] : 0;
        loc += v[j];
    }
    int run = loc;
#pragma unroll
    for (int off = 1; off < 64; off <<= 1) {
        int n = __shfl_up(run, off);
        if (lane >= off) run += n;
    }
    if (lane == 63) wsum[wid] = run;
    __syncthreads();
    int woff = partials[blockIdx.x];
#pragma unroll
    for (int wv = 0; wv < 4; wv++)
        if (wv < wid) woff += wsum[wv];
    int excl = woff + run - loc;
#pragma unroll
    for (int j = 0; j < 4; j++) {
        int idx = i0 + j;
        if (idx < NN) {
            row_off[idx] = excl;
            inv_deg[idx] = 1.0f / fmaxf((float)v[j], 1.0f);
            excl += v[j];
        }
    }
}

// ---------- fp32 -> bf16 convert (x) ----------
__global__ void k_cvt(const float* __restrict__ x, unsigned short* __restrict__ xb) {
    int t = blockIdx.x * blockDim.x + threadIdx.x;
    if (t >= NN * F / 8) return;
    const float4* x4 = (const float4*)x;
    float4 a = x4[t * 2], b = x4[t * 2 + 1];
    u16x8 o;
    o[0] = b16(a.x); o[1] = b16(a.y); o[2] = b16(a.z); o[3] = b16(a.w);
    o[4] = b16(b.x); o[5] = b16(b.y); o[6] = b16(b.z); o[7] = b16(b.w);
    ((u16x8*)xb)[t] = o;
}

// ---------- pack weights into MFMA-fragment-linear bf16 ----------
__global__ void k_pack_all(const float* __restrict__ Ws0, const float* __restrict__ Wn0,
                           const float* __restrict__ Ws1, const float* __restrict__ Wn1,
                           const float* __restrict__ Ws2, const float* __restrict__ Wn2,
                           unsigned short* __restrict__ wp) {
    int idx = blockIdx.x * blockDim.x + threadIdx.x;
    if (idx >= 77824) return;
    const float* W;
    int base, ncols;
    if (idx < 65536) {
        int m = idx >> 14;
        W = (m == 0) ? Ws0 : (m == 1) ? Wn0 : (m == 2) ? Ws1 : Wn1;
        base = m << 14;
        ncols = 128;
    } else {
        int m = (idx - 65536) / 6144;
        W = m ? Wn2 : Ws2;
        base = 65536 + m * 6144;
        ncols = NCLS;
    }
    int li = idx - base;
    int nt = li >> 11;
    int r = li & 2047;
    int kk = r >> 9;
    int r2 = r & 511;
    int lane = r2 >> 3;
    int j = r2 & 7;
    int k = kk * 32 + ((lane >> 4) << 3) + j;
    int n = nt * 16 + (lane & 15);
    float v = (n < ncols) ? W[k * ncols + n] : 0.f;
    wp[idx] = b16(v);
}

// ---------- mean aggregation: wave/node, unconditional clamped loads, MLP x16 ----------
__global__ void __launch_bounds__(256) k_aggb(const unsigned int* __restrict__ hb32,
                                              const int* __restrict__ row_off,
                                              const int* __restrict__ col,
                                              const float* __restrict__ inv_deg,
                                              unsigned int* __restrict__ ab32) {
    int node = (blockIdx.x * blockDim.x + threadIdx.x) >> 6;
    int lane = threadIdx.x & 63;
    if (node >= NN) return;
    int b = row_off[node], e = row_off[node + 1];
    int deg = e - b;
    float ax = 0.f, ay = 0.f;
    const unsigned int* hp = hb32 + lane;
    for (int base = 0; base < deg; base += 64) {
        int cnt = deg - base;
        if (cnt > 64) cnt = 64;
        int myc = col[b + base + (lane < cnt ? lane : 0)];
        for (int jj = 0; jj < cnt; jj += 16) {
            int cs[16];
            unsigned int us[16];
#pragma unroll
            for (int k = 0; k < 16; k++) {
                int idx = jj + k;
                cs[k] = __shfl(myc, idx < cnt ? idx : 0);
            }
#pragma unroll
            for (int k = 0; k < 16; k++) us[k] = hp[(unsigned)cs[k] * 64u];
#pragma unroll
            for (int k = 0; k < 16; k++) {
                if (jj + k < cnt) {  // wave-uniform
                    ax += bflo(us[k]);
                    ay += bfhi(us[k]);
                }
            }
        }
    }
    float s = inv_deg[node];
    ax *= s; ay *= s;
    ab32[(size_t)node * 64 + lane] = (unsigned int)b16(ax) | ((unsigned int)b16(ay) << 16);
}

// ---------- fused dual-GEMM layer via MFMA ----------
template <bool RELU>
__global__ void __launch_bounds__(256) k_layer(const unsigned short* __restrict__ hb,
                                               const unsigned short* __restrict__ ab,
                                               const unsigned short* __restrict__ wps,
                                               const unsigned short* __restrict__ wpn,
                                               const float* __restrict__ bias,
                                               unsigned short* __restrict__ outb) {
    const int wid = threadIdx.x >> 6, lane = threadIdx.x & 63;
    const int tile0 = blockIdx.x * 64;
    const short8* ws8 = (const short8*)wps;
    const short8* wn8 = (const short8*)wpn;
    short8 wf[2][2][4];
#pragma unroll
    for (int t = 0; t < 2; t++) {
        int nt = 2 * wid + t;
#pragma unroll
        for (int kk = 0; kk < 4; kk++) {
            wf[0][t][kk] = ws8[(nt * 4 + kk) * 64 + lane];
            wf[1][t][kk] = wn8[(nt * 4 + kk) * 64 + lane];
        }
    }
    const int rb = lane & 15, kq = lane >> 4;
    float bv[2];
#pragma unroll
    for (int t = 0; t < 2; t++) bv[t] = bias[(2 * wid + t) * 16 + rb];
    const short8* h8 = (const short8*)hb;
    const short8* a8 = (const short8*)ab;
    f32x4 zero = {0.f, 0.f, 0.f, 0.f};
    f32x4 acc[4][2];
#pragma unroll
    for (int m = 0; m < 4; m++)
#pragma unroll
        for (int t = 0; t < 2; t++) acc[m][t] = zero;
#pragma unroll
    for (int kk = 0; kk < 4; kk++) {
#pragma unroll
        for (int m = 0; m < 4; m++) {
            int row = tile0 + m * 16 + rb;
            int rc = row < NN ? row : NN - 1;
            int idx = rc * 16 + kk * 4 + kq;
            short8 af = h8[idx];
            short8 gf = a8[idx];
            acc[m][0] = MFMA16(af, wf[0][0][kk], acc[m][0]);
            acc[m][1] = MFMA16(af, wf[0][1][kk], acc[m][1]);
            acc[m][0] = MFMA16(gf, wf[1][0][kk], acc[m][0]);
            acc[m][1] = MFMA16(gf, wf[1][1][kk], acc[m][1]);
        }
    }
#pragma unroll
    for (int m = 0; m < 4; m++) {
#pragma unroll
        for (int reg = 0; reg < 4; reg++) {
            int row = tile0 + m * 16 + kq * 4 + reg;
            if (row < NN) {
#pragma unroll
                for (int t = 0; t < 2; t++) {
                    float v = acc[m][t][reg] + bv[t];
                    if (RELU) v = fmaxf(v, 0.f);
                    outb[(size_t)row * F + (2 * wid + t) * 16 + rb] = b16(v);
                }
            }
        }
    }
}

// ---------- final layer: MFMA (N=48) + log_softmax, fp32 out ----------
__global__ void __launch_bounds__(512) k_out(const unsigned short* __restrict__ hb,
                                             const unsigned short* __restrict__ ab,
                                             const unsigned short* __restrict__ wps,
                                             const unsigned short* __restrict__ wpn,
                                             const float* __restrict__ bias,
                                             float* __restrict__ out) {
    const int wid = threadIdx.x >> 6, lane = threadIdx.x & 63;
    const int R0 = blockIdx.x * 128 + wid * 16;
    const short8* ws8 = (const short8*)wps;
    const short8* wn8 = (const short8*)wpn;
    short8 wf[2][3][4];
#pragma unroll
    for (int nt = 0; nt < 3; nt++)
#pragma unroll
        for (int kk = 0; kk < 4; kk++) {
            wf[0][nt][kk] = ws8[(nt * 4 + kk) * 64 + lane];
            wf[1][nt][kk] = wn8[(nt * 4 + kk) * 64 + lane];
        }
    const int rb = lane & 15, kq = lane >> 4;
    float bv[3];
    bool valid[3];
#pragma unroll
    for (int nt = 0; nt < 3; nt++) {
        int c = nt * 16 + rb;
        valid[nt] = c < NCLS;
        bv[nt] = valid[nt] ? bias[c] : 0.f;
    }
    const short8* h8 = (const short8*)hb;
    const short8* a8 = (const short8*)ab;
    f32x4 zero = {0.f, 0.f, 0.f, 0.f};
    f32x4 acc[3] = {zero, zero, zero};
    int rowr = R0 + rb;
    int rc = rowr < NN ? rowr : NN - 1;
#pragma unroll
    for (int kk = 0; kk < 4; kk++) {
        int idx = rc * 16 + kk * 4 + kq;
        short8 af = h8[idx];
        short8 gf = a8[idx];
#pragma unroll
        for (int nt = 0; nt < 3; nt++) {
            acc[nt] = MFMA16(af, wf[0][nt][kk], acc[nt]);
            acc[nt] = MFMA16(gf, wf[1][nt][kk], acc[nt]);
        }
    }
#pragma unroll
    for (int reg = 0; reg < 4; reg++) {
        int row = R0 + kq * 4 + reg;
        float v[3];
        float mx = -1e30f;
#pragma unroll
        for (int nt = 0; nt < 3; nt++) {
            v[nt] = acc[nt][reg] + bv[nt];
            if (valid[nt]) mx = fmaxf(mx, v[nt]);
        }
        for (int off = 1; off < 16; off <<= 1) mx = fmaxf(mx, __shfl_xor(mx, off));
        float s = 0.f;
#pragma unroll
        for (int nt = 0; nt < 3; nt++)
            if (valid[nt]) s += expf(v[nt] - mx);
        for (int off = 1; off < 16; off <<= 1) s += __shfl_xor(s, off);
        float L = mx + logf(s);
        if (row < NN) {
#pragma unroll
            for (int nt = 0; nt < 3; nt++)
                if (valid[nt]) out[(size_t)row * NCLS + nt * 16 + rb] = v[nt] - L;
        }
    }
}

extern "C" void kernel_launch(void* const* d_in, const int* in_sizes, int n_in,
                              void* d_out, int out_size, void* d_ws, size_t ws_size,
                              hipStream_t stream) {
    (void)in_sizes; (void)n_in; (void)out_size; (void)ws_size;
    const float* x = (const float*)d_in[0];
    const int* src = (const int*)d_in[1];
    const int* dst = (const int*)d_in[2];
    const float* Ws0 = (const float*)d_in[3];
    const float* Wn0 = (const float*)d_in[4];
    const float* b0 = (const float*)d_in[5];
    const float* Ws1 = (const float*)d_in[6];
    const float* Wn1 = (const float*)d_in[7];
    const float* b1 = (const float*)d_in[8];
    const float* Ws2 = (const float*)d_in[9];
    const float* Wn2 = (const float*)d_in[10];
    const float* b2 = (const float*)d_in[11];
    float* out = (float*)d_out;

    char* w = (char*)d_ws;
    size_t off = 0;
    auto alloc = [&](size_t bytes) -> char* {
        char* p = w + off;
        off = (off + bytes + 255) & ~(size_t)255;
        return p;
    };
    int* deg = (int*)alloc((size_t)NN * 4);
    int* row_off = (int*)alloc((size_t)(NN + 1) * 4);
    int* col = (int*)alloc((size_t)NE * 4);
    float* inv_deg = (float*)alloc((size_t)NN * 4);
    int* partials = (int*)alloc((size_t)SCAN_B * 4);
    int* bucket_cnt = (int*)alloc((size_t)(BUCKETS + 1) * 4);
    int* bucket_off = (int*)alloc((size_t)(BUCKETS + 1) * 4);
    int* bcursor = (int*)alloc((size_t)(BUCKETS + 1) * 4);
    int2* ebuf = (int2*)alloc((size_t)NE * 8);
    unsigned short* xb = (unsigned short*)alloc((size_t)NN * F * 2);
    unsigned short* aggb = (unsigned short*)alloc((size_t)NN * F * 2);
    unsigned short* h1b = (unsigned short*)alloc((size_t)NN * F * 2);
    unsigned short* h2b = (unsigned short*)alloc((size_t)NN * F * 2);
    unsigned short* wp = (unsigned short*)alloc((size_t)77824 * 2);

    hipMemsetAsync(bucket_cnt, 0, (size_t)(BUCKETS + 1) * 4, stream);

    // CSR build: bucket edges, then per-bucket deg/fill
    k_bhist<<<ABLK, 256, 0, stream>>>(dst, bucket_cnt);
    k_bscan<<<1, 64, 0, stream>>>(bucket_cnt, bucket_off, bcursor);
    k_bscatter<<<ABLK, 256, 0, stream>>>(src, dst, bcursor, ebuf);
    k_bdeg<<<BUCKETS, 256, 0, stream>>>(ebuf, bucket_off, deg);
    k_part<<<SCAN_B, 256, 0, stream>>>(deg, partials);
    k_scanpart<<<1, 64, 0, stream>>>(partials, row_off);
    k_offsets<<<SCAN_B, 256, 0, stream>>>(deg, partials, row_off, inv_deg);
    k_bfill<<<BUCKETS, 256, 0, stream>>>(ebuf, bucket_off, row_off, col);

    k_cvt<<<(NN * F / 8 + 255) / 256, 256, 0, stream>>>(x, xb);
    k_pack_all<<<(77824 + 255) / 256, 256, 0, stream>>>(Ws0, Wn0, Ws1, Wn1, Ws2, Wn2, wp);

    unsigned short* wS0 = wp;
    unsigned short* wN0 = wp + 16384;
    unsigned short* wS1 = wp + 32768;
    unsigned short* wN1 = wp + 49152;
    unsigned short* wS2 = wp + 65536;
    unsigned short* wN2 = wp + 71680;

    const int AGG_B = NN * 64 / 256;            // 25000 (wave per node)
    const int LYR_B = (NN + 63) / 64;           // 1563
    const int OUT_B = (NN + 127) / 128;         // 782

    // layer 0
    k_aggb<<<AGG_B, 256, 0, stream>>>((const unsigned int*)xb, row_off, col, inv_deg,
                                      (unsigned int*)aggb);
    k_layer<true><<<LYR_B, 256, 0, stream>>>(xb, aggb, wS0, wN0, b0, h1b);
    // layer 1
    k_aggb<<<AGG_B, 256, 0, stream>>>((const unsigned int*)h1b, row_off, col, inv_deg,
                                      (unsigned int*)aggb);
    k_layer<true><<<LYR_B, 256, 0, stream>>>(h1b, aggb, wS1, wN1, b1, h2b);
    // layer 2
    k_aggb<<<AGG_B, 256, 0, stream>>>((const unsigned int*)h2b, row_off, col, inv_deg,
                                      (unsigned int*)aggb);
    k_out<<<OUT_B, 512, 0, stream>>>(h2b, aggb, wS2, wN2, b2, out);
}

// Round 11
// 334.029 us; speedup vs baseline: 1.5091x; 1.0633x over previous
//
#include <hip/hip_runtime.h>
#include <hip/hip_bf16.h>

#define NN 100000
#define NE 1600000
#define F 128
#define NCLS 47

#define SCAN_B 98      // ceil(NN / 1024) for node-level scan
#define NPB 256        // nodes per bucket (d >> 8)
#define BUCKETS 391    // ceil(NN / NPB)
#define ABLK 512       // phase-A blocks
#define ACHUNK (NE / ABLK)  // 3125 edges per A-block

typedef __attribute__((ext_vector_type(8))) short short8;
typedef __attribute__((ext_vector_type(8))) unsigned short u16x8;
typedef __attribute__((ext_vector_type(4))) float f32x4;

#define MFMA16(A, B, C) __builtin_amdgcn_mfma_f32_16x16x32_bf16(A, B, C, 0, 0, 0)

__device__ __forceinline__ unsigned short b16(float f) {
    unsigned int u = __builtin_bit_cast(unsigned int, f);
    unsigned int r = u + 0x7FFFu + ((u >> 16) & 1u);  // RTN-even
    return (unsigned short)(r >> 16);
}
__device__ __forceinline__ float bflo(unsigned int u) { return __builtin_bit_cast(float, u << 16); }
__device__ __forceinline__ float bfhi(unsigned int u) { return __builtin_bit_cast(float, u & 0xFFFF0000u); }

// ---------- CSR build, phase A: bucket the edges ----------
__global__ void __launch_bounds__(256) k_bhist(const int* __restrict__ dst,
                                               int* __restrict__ bucket_cnt) {
    __shared__ int hist[BUCKETS];
    const int t = threadIdx.x;
    for (int i = t; i < BUCKETS; i += 256) hist[i] = 0;
    __syncthreads();
    const int e0 = blockIdx.x * ACHUNK;
    for (int i = t; i < ACHUNK; i += 256) atomicAdd(&hist[dst[e0 + i] >> 8], 1);
    __syncthreads();
    for (int i = t; i < BUCKETS; i += 256)
        if (hist[i]) atomicAdd(&bucket_cnt[i], hist[i]);
}

__global__ void k_bscan(const int* __restrict__ bucket_cnt, int* __restrict__ bucket_off,
                        int* __restrict__ cursor) {
    const int lane = threadIdx.x & 63;
    int run = 0;
#pragma unroll
    for (int c = 0; c < 7; c++) {
        int idx = c * 64 + lane;
        int v = (idx < BUCKETS) ? bucket_cnt[idx] : 0;
        int s = v;
#pragma unroll
        for (int off = 1; off < 64; off <<= 1) {
            int n = __shfl_up(s, off);
            if (lane >= off) s += n;
        }
        int excl = run + s - v;
        if (idx <= BUCKETS) {
            bucket_off[idx] = excl;
            cursor[idx] = excl;
        }
        run += __shfl(s, 63);
    }
}

__global__ void __launch_bounds__(256) k_bscatter(const int* __restrict__ src,
                                                  const int* __restrict__ dst,
                                                  int* __restrict__ cursor,
                                                  int2* __restrict__ ebuf) {
    __shared__ int hist[BUCKETS];
    __shared__ int base[BUCKETS];
    __shared__ int rank[BUCKETS];
    const int t = threadIdx.x;
    for (int i = t; i < BUCKETS; i += 256) {
        hist[i] = 0;
        rank[i] = 0;
    }
    __syncthreads();
    const int e0 = blockIdx.x * ACHUNK;
    for (int i = t; i < ACHUNK; i += 256) atomicAdd(&hist[dst[e0 + i] >> 8], 1);
    __syncthreads();
    for (int i = t; i < BUCKETS; i += 256) {
        int h = hist[i];
        base[i] = h ? atomicAdd(&cursor[i], h) : 0;
    }
    __syncthreads();
    for (int i = t; i < ACHUNK; i += 256) {
        int s = src[e0 + i];
        int d = dst[e0 + i];
        int b = d >> 8;
        int r = atomicAdd(&rank[b], 1);
        ebuf[base[b] + r] = make_int2(s, d);
    }
}

// ---------- CSR build, phase B: per-bucket (256 nodes) ----------
__global__ void __launch_bounds__(256) k_bdeg(const int2* __restrict__ ebuf,
                                              const int* __restrict__ bucket_off,
                                              int* __restrict__ deg) {
    __shared__ int cnt[NPB];
    const int t = threadIdx.x;
    cnt[t] = 0;
    __syncthreads();
    const int e0 = bucket_off[blockIdx.x], e1 = bucket_off[blockIdx.x + 1];
    for (int i = e0 + t; i < e1; i += 256) atomicAdd(&cnt[ebuf[i].y & 255], 1);
    __syncthreads();
    int node = (blockIdx.x << 8) + t;
    if (node < NN) deg[node] = cnt[t];
}

__global__ void __launch_bounds__(256) k_bfill(const int2* __restrict__ ebuf,
                                               const int* __restrict__ bucket_off,
                                               const int* __restrict__ row_off,
                                               int* __restrict__ col) {
    __shared__ int ro[NPB];
    __shared__ int cur[NPB];
    const int t = threadIdx.x;
    int node = (blockIdx.x << 8) + t;
    ro[t] = (node < NN) ? row_off[node] : 0;
    cur[t] = 0;
    __syncthreads();
    const int e0 = bucket_off[blockIdx.x], e1 = bucket_off[blockIdx.x + 1];
    for (int i = e0 + t; i < e1; i += 256) {
        int2 e = ebuf[i];
        int d = e.y & 255;
        int p = atomicAdd(&cur[d], 1);
        col[ro[d] + p] = e.x;
    }
}

// ---------- node-level scan (row_off, inv_deg) ----------
__global__ void __launch_bounds__(256) k_part(const int* __restrict__ deg,
                                              int* __restrict__ partials) {
    __shared__ int ws[4];
    const int t = threadIdx.x, lane = t & 63, wid = t >> 6;
    int i0 = blockIdx.x * 1024 + t * 4;
    int s = 0;
    if (i0 + 3 < NN) {
        int4 v = *(const int4*)&deg[i0];
        s = v.x + v.y + v.z + v.w;
    } else {
#pragma unroll
        for (int j = 0; j < 4; j++) {
            int idx = i0 + j;
            if (idx < NN) s += deg[idx];
        }
    }
#pragma unroll
    for (int off = 1; off < 64; off <<= 1) s += __shfl_xor(s, off);
    if (lane == 0) ws[wid] = s;
    __syncthreads();
    if (t == 0) partials[blockIdx.x] = ws[0] + ws[1] + ws[2] + ws[3];
}

__global__ void k_scanpart(int* __restrict__ partials, int* __restrict__ row_off) {
    const int lane = threadIdx.x & 63;
    int v0 = (lane < SCAN_B) ? partials[lane] : 0;
    int i1 = lane + 64;
    int v1 = (i1 < SCAN_B) ? partials[i1] : 0;
    int s0 = v0;
#pragma unroll
    for (int off = 1; off < 64; off <<= 1) {
        int n = __shfl_up(s0, off);
        if (lane >= off) s0 += n;
    }
    int tot0 = __shfl(s0, 63);
    int s1 = v1;
#pragma unroll
    for (int off = 1; off < 64; off <<= 1) {
        int n = __shfl_up(s1, off);
        if (lane >= off) s1 += n;
    }
    if (lane < SCAN_B) partials[lane] = s0 - v0;
    if (i1 < SCAN_B) partials[i1] = tot0 + s1 - v1;
    if (lane == 0) row_off[NN] = NE;
}

__global__ void __launch_bounds__(256) k_offsets(const int* __restrict__ deg,
                                                 const int* __restrict__ partials,
                                                 int* __restrict__ row_off,
                                                 float* __restrict__ inv_deg) {
    __shared__ int wsum[4];
    const int t = threadIdx.x, lane = t & 63, wid = t >> 6;
    int i0 = blockIdx.x * 1024 + t * 4;
    int v[4];
    int loc = 0;
#pragma unroll
    for (int j = 0; j < 4; j++) {
        int idx = i0 + j;
        v[j] = (idx < NN) ? deg[idx] : 0;
        loc += v[j];
    }
    int run = loc;
#pragma unroll
    for (int off = 1; off < 64; off <<= 1) {
        int n = __shfl_up(run, off);
        if (lane >= off) run += n;
    }
    if (lane == 63) wsum[wid] = run;
    __syncthreads();
    int woff = partials[blockIdx.x];
#pragma unroll
    for (int wv = 0; wv < 4; wv++)
        if (wv < wid) woff += wsum[wv];
    int excl = woff + run - loc;
#pragma unroll
    for (int j = 0; j < 4; j++) {
        int idx = i0 + j;
        if (idx < NN) {
            row_off[idx] = excl;
            inv_deg[idx] = 1.0f / fmaxf((float)v[j], 1.0f);
            excl += v[j];
        }
    }
}

// ---------- fp32 -> bf16 convert (x) ----------
__global__ void k_cvt(const float* __restrict__ x, unsigned short* __restrict__ xb) {
    int t = blockIdx.x * blockDim.x + threadIdx.x;
    if (t >= NN * F / 8) return;
    const float4* x4 = (const float4*)x;
    float4 a = x4[t * 2], b = x4[t * 2 + 1];
    u16x8 o;
    o[0] = b16(a.x); o[1] = b16(a.y); o[2] = b16(a.z); o[3] = b16(a.w);
    o[4] = b16(b.x); o[5] = b16(b.y); o[6] = b16(b.z); o[7] = b16(b.w);
    ((u16x8*)xb)[t] = o;
}

// ---------- pack weights into MFMA-fragment-linear bf16 ----------
__global__ void k_pack_all(const float* __restrict__ Ws0, const float* __restrict__ Wn0,
                           const float* __restrict__ Ws1, const float* __restrict__ Wn1,
                           const float* __restrict__ Ws2, const float* __restrict__ Wn2,
                           unsigned short* __restrict__ wp) {
    int idx = blockIdx.x * blockDim.x + threadIdx.x;
    if (idx >= 77824) return;
    const float* W;
    int base, ncols;
    if (idx < 65536) {
        int m = idx >> 14;
        W = (m == 0) ? Ws0 : (m == 1) ? Wn0 : (m == 2) ? Ws1 : Wn1;
        base = m << 14;
        ncols = 128;
    } else {
        int m = (idx - 65536) / 6144;
        W = m ? Wn2 : Ws2;
        base = 65536 + m * 6144;
        ncols = NCLS;
    }
    int li = idx - base;
    int nt = li >> 11;
    int r = li & 2047;
    int kk = r >> 9;
    int r2 = r & 511;
    int lane = r2 >> 3;
    int j = r2 & 7;
    int k = kk * 32 + ((lane >> 4) << 3) + j;
    int n = nt * 16 + (lane & 15);
    float v = (n < ncols) ? W[k * ncols + n] : 0.f;
    wp[idx] = b16(v);
}

// ---------- mean aggregation (128-wide): 4 rows per wave-instr via dwordx4 ----------
// lane l: row group g=l>>4, feature slot fl=l&15 (bf16 features fl*8..fl*8+7)
__global__ void __launch_bounds__(256) k_aggb(const uint4* __restrict__ h4,
                                              const int* __restrict__ row_off,
                                              const int* __restrict__ col,
                                              const float* __restrict__ inv_deg,
                                              uint4* __restrict__ a4) {
    int node = (blockIdx.x * blockDim.x + threadIdx.x) >> 6;
    int lane = threadIdx.x & 63;
    if (node >= NN) return;
    int b = row_off[node], e = row_off[node + 1];
    int deg = e - b;
    const int g = lane >> 4, fl = lane & 15;
    float acc[8];
#pragma unroll
    for (int i = 0; i < 8; i++) acc[i] = 0.f;
    for (int base = 0; base < deg; base += 64) {
        int cnt = deg - base;
        if (cnt > 64) cnt = 64;
        int myc = col[b + base + (lane < cnt ? lane : 0)];
        for (int jj = 0; jj < cnt; jj += 16) {
            uint4 u[4];
#pragma unroll
            for (int k2 = 0; k2 < 4; k2++) {
                int r = jj + k2 * 4 + g;
                int c = __shfl(myc, r < cnt ? r : 0);
                u[k2] = h4[(size_t)(unsigned)c * 16u + fl];
            }
#pragma unroll
            for (int k2 = 0; k2 < 4; k2++) {
                int r = jj + k2 * 4 + g;
                unsigned m = (r < cnt) ? 0xFFFFFFFFu : 0u;
                uint4 v = u[k2];
                v.x &= m; v.y &= m; v.z &= m; v.w &= m;
                acc[0] += bflo(v.x); acc[1] += bfhi(v.x);
                acc[2] += bflo(v.y); acc[3] += bfhi(v.y);
                acc[4] += bflo(v.z); acc[5] += bfhi(v.z);
                acc[6] += bflo(v.w); acc[7] += bfhi(v.w);
            }
        }
    }
#pragma unroll
    for (int i = 0; i < 8; i++) {
        acc[i] += __shfl_xor(acc[i], 16);
        acc[i] += __shfl_xor(acc[i], 32);
    }
    if (g == 0) {
        float s = inv_deg[node];
        uint4 o;
        o.x = (unsigned)b16(acc[0] * s) | ((unsigned)b16(acc[1] * s) << 16);
        o.y = (unsigned)b16(acc[2] * s) | ((unsigned)b16(acc[3] * s) << 16);
        o.z = (unsigned)b16(acc[4] * s) | ((unsigned)b16(acc[5] * s) << 16);
        o.w = (unsigned)b16(acc[6] * s) | ((unsigned)b16(acc[7] * s) << 16);
        a4[(size_t)node * 16 + fl] = o;
    }
}

// ---------- mean aggregation (64-wide padded rows of hw2): 8 rows per wave-instr ----------
// lane l: row group g=l>>3, feature slot fl=l&7 (bf16 features fl*8..+8); fp32 out (inv_deg folded)
__global__ void __launch_bounds__(256) k_agg48(const uint4* __restrict__ hw4,
                                               const int* __restrict__ row_off,
                                               const int* __restrict__ col,
                                               const float* __restrict__ inv_deg,
                                               float4* __restrict__ aggf4) {
    int node = (blockIdx.x * blockDim.x + threadIdx.x) >> 6;
    int lane = threadIdx.x & 63;
    if (node >= NN) return;
    int b = row_off[node], e = row_off[node + 1];
    int deg = e - b;
    const int g = lane >> 3, fl = lane & 7;
    float acc[8];
#pragma unroll
    for (int i = 0; i < 8; i++) acc[i] = 0.f;
    for (int base = 0; base < deg; base += 64) {
        int cnt = deg - base;
        if (cnt > 64) cnt = 64;
        int myc = col[b + base + (lane < cnt ? lane : 0)];
        for (int jj = 0; jj < cnt; jj += 16) {
            uint4 u[2];
#pragma unroll
            for (int k2 = 0; k2 < 2; k2++) {
                int r = jj + k2 * 8 + g;
                int c = __shfl(myc, r < cnt ? r : 0);
                u[k2] = hw4[(size_t)(unsigned)c * 8u + fl];
            }
#pragma unroll
            for (int k2 = 0; k2 < 2; k2++) {
                int r = jj + k2 * 8 + g;
                unsigned m = (r < cnt) ? 0xFFFFFFFFu : 0u;
                uint4 v = u[k2];
                v.x &= m; v.y &= m; v.z &= m; v.w &= m;
                acc[0] += bflo(v.x); acc[1] += bfhi(v.x);
                acc[2] += bflo(v.y); acc[3] += bfhi(v.y);
                acc[4] += bflo(v.z); acc[5] += bfhi(v.z);
                acc[6] += bflo(v.w); acc[7] += bfhi(v.w);
            }
        }
    }
#pragma unroll
    for (int i = 0; i < 8; i++) {
        acc[i] += __shfl_xor(acc[i], 8);
        acc[i] += __shfl_xor(acc[i], 16);
        acc[i] += __shfl_xor(acc[i], 32);
    }
    if (lane < 8) {
        float s = inv_deg[node];
        float4 o0 = make_float4(acc[0] * s, acc[1] * s, acc[2] * s, acc[3] * s);
        float4 o1 = make_float4(acc[4] * s, acc[5] * s, acc[6] * s, acc[7] * s);
        aggf4[(size_t)node * 16 + fl * 2] = o0;
        aggf4[(size_t)node * 16 + fl * 2 + 1] = o1;
    }
}

// ---------- fused dual-GEMM layer via MFMA ----------
template <bool RELU>
__global__ void __launch_bounds__(256) k_layer(const unsigned short* __restrict__ hb,
                                               const unsigned short* __restrict__ ab,
                                               const unsigned short* __restrict__ wps,
                                               const unsigned short* __restrict__ wpn,
                                               const float* __restrict__ bias,
                                               unsigned short* __restrict__ outb) {
    const int wid = threadIdx.x >> 6, lane = threadIdx.x & 63;
    const int tile0 = blockIdx.x * 64;
    const short8* ws8 = (const short8*)wps;
    const short8* wn8 = (const short8*)wpn;
    short8 wf[2][2][4];
#pragma unroll
    for (int t = 0; t < 2; t++) {
        int nt = 2 * wid + t;
#pragma unroll
        for (int kk = 0; kk < 4; kk++) {
            wf[0][t][kk] = ws8[(nt * 4 + kk) * 64 + lane];
            wf[1][t][kk] = wn8[(nt * 4 + kk) * 64 + lane];
        }
    }
    const int rb = lane & 15, kq = lane >> 4;
    float bv[2];
#pragma unroll
    for (int t = 0; t < 2; t++) bv[t] = bias[(2 * wid + t) * 16 + rb];
    const short8* h8 = (const short8*)hb;
    const short8* a8 = (const short8*)ab;
    f32x4 zero = {0.f, 0.f, 0.f, 0.f};
    f32x4 acc[4][2];
#pragma unroll
    for (int m = 0; m < 4; m++)
#pragma unroll
        for (int t = 0; t < 2; t++) acc[m][t] = zero;
#pragma unroll
    for (int kk = 0; kk < 4; kk++) {
#pragma unroll
        for (int m = 0; m < 4; m++) {
            int row = tile0 + m * 16 + rb;
            int rc = row < NN ? row : NN - 1;
            int idx = rc * 16 + kk * 4 + kq;
            short8 af = h8[idx];
            short8 gf = a8[idx];
            acc[m][0] = MFMA16(af, wf[0][0][kk], acc[m][0]);
            acc[m][1] = MFMA16(af, wf[0][1][kk], acc[m][1]);
            acc[m][0] = MFMA16(gf, wf[1][0][kk], acc[m][0]);
            acc[m][1] = MFMA16(gf, wf[1][1][kk], acc[m][1]);
        }
    }
#pragma unroll
    for (int m = 0; m < 4; m++) {
#pragma unroll
        for (int reg = 0; reg < 4; reg++) {
            int row = tile0 + m * 16 + kq * 4 + reg;
            if (row < NN) {
#pragma unroll
                for (int t = 0; t < 2; t++) {
                    float v = acc[m][t][reg] + bv[t];
                    if (RELU) v = fmaxf(v, 0.f);
                    outb[(size_t)row * F + (2 * wid + t) * 16 + rb] = b16(v);
                }
            }
        }
    }
}

// ---------- hw2 = h2 @ Wn2 (bf16 out, [NN][64], cols 48-63 unwritten/unused) ----------
__global__ void __launch_bounds__(512) k_nmul(const unsigned short* __restrict__ hb,
                                              const unsigned short* __restrict__ wpn,
                                              unsigned short* __restrict__ hw) {
    const int wid = threadIdx.x >> 6, lane = threadIdx.x & 63;
    const int R0 = blockIdx.x * 128 + wid * 16;
    const short8* wn8 = (const short8*)wpn;
    short8 wf[3][4];
#pragma unroll
    for (int nt = 0; nt < 3; nt++)
#pragma unroll
        for (int kk = 0; kk < 4; kk++) wf[nt][kk] = wn8[(nt * 4 + kk) * 64 + lane];
    const int rb = lane & 15, kq = lane >> 4;
    const short8* h8 = (const short8*)hb;
    f32x4 zero = {0.f, 0.f, 0.f, 0.f};
    f32x4 acc[3] = {zero, zero, zero};
    int rowr = R0 + rb;
    int rc = rowr < NN ? rowr : NN - 1;
#pragma unroll
    for (int kk = 0; kk < 4; kk++) {
        short8 af = h8[rc * 16 + kk * 4 + kq];
#pragma unroll
        for (int nt = 0; nt < 3; nt++) acc[nt] = MFMA16(af, wf[nt][kk], acc[nt]);
    }
#pragma unroll
    for (int reg = 0; reg < 4; reg++) {
        int row = R0 + kq * 4 + reg;
        if (row < NN) {
#pragma unroll
            for (int nt = 0; nt < 3; nt++)
                hw[(size_t)row * 64 + nt * 16 + rb] = b16(acc[nt][reg]);
        }
    }
}

// ---------- final layer: self-GEMM + aggregated hw + bias + log_softmax ----------
__global__ void __launch_bounds__(512) k_out2(const unsigned short* __restrict__ hb,
                                              const float* __restrict__ aggf,
                                              const unsigned short* __restrict__ wps,
                                              const float* __restrict__ bias,
                                              float* __restrict__ out) {
    const int wid = threadIdx.x >> 6, lane = threadIdx.x & 63;
    const int R0 = blockIdx.x * 128 + wid * 16;
    const short8* ws8 = (const short8*)wps;
    short8 wf[3][4];
#pragma unroll
    for (int nt = 0; nt < 3; nt++)
#pragma unroll
        for (int kk = 0; kk < 4; kk++) wf[nt][kk] = ws8[(nt * 4 + kk) * 64 + lane];
    const int rb = lane & 15, kq = lane >> 4;
    float bv[3];
    bool valid[3];
#pragma unroll
    for (int nt = 0; nt < 3; nt++) {
        int c = nt * 16 + rb;
        valid[nt] = c < NCLS;
        bv[nt] = valid[nt] ? bias[c] : 0.f;
    }
    const short8* h8 = (const short8*)hb;
    f32x4 zero = {0.f, 0.f, 0.f, 0.f};
    f32x4 acc[3] = {zero, zero, zero};
    int rowr = R0 + rb;
    int rc = rowr < NN ? rowr : NN - 1;
#pragma unroll
    for (int kk = 0; kk < 4; kk++) {
        short8 af = h8[rc * 16 + kk * 4 + kq];
#pragma unroll
        for (int nt = 0; nt < 3; nt++) acc[nt] = MFMA16(af, wf[nt][kk], acc[nt]);
    }
#pragma unroll
    for (int reg = 0; reg < 4; reg++) {
        int row = R0 + kq * 4 + reg;
        int rc2 = row < NN ? row : NN - 1;
        float v[3];
        float mx = -1e30f;
#pragma unroll
        for (int nt = 0; nt < 3; nt++) {
            float av = aggf[(size_t)rc2 * 64 + nt * 16 + rb];
            v[nt] = acc[nt][reg] + av + bv[nt];
            if (valid[nt]) mx = fmaxf(mx, v[nt]);
        }
        for (int off = 1; off < 16; off <<= 1) mx = fmaxf(mx, __shfl_xor(mx, off));
        float s = 0.f;
#pragma unroll
        for (int nt = 0; nt < 3; nt++)
            if (valid[nt]) s += expf(v[nt] - mx);
        for (int off = 1; off < 16; off <<= 1) s += __shfl_xor(s, off);
        float L = mx + logf(s);
        if (row < NN) {
#pragma unroll
            for (int nt = 0; nt < 3; nt++)
                if (valid[nt]) out[(size_t)row * NCLS + nt * 16 + rb] = v[nt] - L;
        }
    }
}

extern "C" void kernel_launch(void* const* d_in, const int* in_sizes, int n_in,
                              void* d_out, int out_size, void* d_ws, size_t ws_size,
                              hipStream_t stream) {
    (void)in_sizes; (void)n_in; (void)out_size; (void)ws_size;
    const float* x = (const float*)d_in[0];
    const int* src = (const int*)d_in[1];
    const int* dst = (const int*)d_in[2];
    const float* Ws0 = (const float*)d_in[3];
    const float* Wn0 = (const float*)d_in[4];
    const float* b0 = (const float*)d_in[5];
    const float* Ws1 = (const float*)d_in[6];
    const float* Wn1 = (const float*)d_in[7];
    const float* b1 = (const float*)d_in[8];
    const float* Ws2 = (const float*)d_in[9];
    const float* Wn2 = (const float*)d_in[10];
    const float* b2 = (const float*)d_in[11];
    float* out = (float*)d_out;

    char* w = (char*)d_ws;
    size_t off = 0;
    auto alloc = [&](size_t bytes) -> char* {
        char* p = w + off;
        off = (off + bytes + 255) & ~(size_t)255;
        return p;
    };
    int* deg = (int*)alloc((size_t)NN * 4);
    int* row_off = (int*)alloc((size_t)(NN + 1) * 4);
    int* col = (int*)alloc((size_t)NE * 4);
    float* inv_deg = (float*)alloc((size_t)NN * 4);
    int* partials = (int*)alloc((size_t)SCAN_B * 4);
    int* bucket_cnt = (int*)alloc((size_t)(BUCKETS + 1) * 4);
    int* bucket_off = (int*)alloc((size_t)(BUCKETS + 1) * 4);
    int* bcursor = (int*)alloc((size_t)(BUCKETS + 1) * 4);
    int2* ebuf = (int2*)alloc((size_t)NE * 8);        // reused as hw2 (12.8MB) after CSR build
    unsigned short* xb = (unsigned short*)alloc((size_t)NN * F * 2);
    unsigned short* aggb = (unsigned short*)alloc((size_t)NN * F * 2);  // reused as agg2f (fp32 [NN][64])
    unsigned short* h1b = (unsigned short*)alloc((size_t)NN * F * 2);
    unsigned short* h2b = (unsigned short*)alloc((size_t)NN * F * 2);
    unsigned short* wp = (unsigned short*)alloc((size_t)77824 * 2);

    unsigned short* hw2b = (unsigned short*)ebuf;     // [NN][64] bf16 = 12.8 MB <= ebuf
    float* agg2f = (float*)aggb;                      // [NN][64] fp32 = 25.6 MB == aggb

    hipMemsetAsync(bucket_cnt, 0, (size_t)(BUCKETS + 1) * 4, stream);

    // CSR build: bucket edges, then per-bucket deg/fill
    k_bhist<<<ABLK, 256, 0, stream>>>(dst, bucket_cnt);
    k_bscan<<<1, 64, 0, stream>>>(bucket_cnt, bucket_off, bcursor);
    k_bscatter<<<ABLK, 256, 0, stream>>>(src, dst, bcursor, ebuf);
    k_bdeg<<<BUCKETS, 256, 0, stream>>>(ebuf, bucket_off, deg);
    k_part<<<SCAN_B, 256, 0, stream>>>(deg, partials);
    k_scanpart<<<1, 64, 0, stream>>>(partials, row_off);
    k_offsets<<<SCAN_B, 256, 0, stream>>>(deg, partials, row_off, inv_deg);
    k_bfill<<<BUCKETS, 256, 0, stream>>>(ebuf, bucket_off, row_off, col);

    k_cvt<<<(NN * F / 8 + 255) / 256, 256, 0, stream>>>(x, xb);
    k_pack_all<<<(77824 + 255) / 256, 256, 0, stream>>>(Ws0, Wn0, Ws1, Wn1, Ws2, Wn2, wp);

    unsigned short* wS0 = wp;
    unsigned short* wN0 = wp + 16384;
    unsigned short* wS1 = wp + 32768;
    unsigned short* wN1 = wp + 49152;
    unsigned short* wS2 = wp + 65536;
    unsigned short* wN2 = wp + 71680;

    const int AGG_B = NN * 64 / 256;            // 25000 (wave per node)
    const int LYR_B = (NN + 63) / 64;           // 1563
    const int OUT_B = (NN + 127) / 128;         // 782

    // layer 0
    k_aggb<<<AGG_B, 256, 0, stream>>>((const uint4*)xb, row_off, col, inv_deg, (uint4*)aggb);
    k_layer<true><<<LYR_B, 256, 0, stream>>>(xb, aggb, wS0, wN0, b0, h1b);
    // layer 1
    k_aggb<<<AGG_B, 256, 0, stream>>>((const uint4*)h1b, row_off, col, inv_deg, (uint4*)aggb);
    k_layer<true><<<LYR_B, 256, 0, stream>>>(h1b, aggb, wS1, wN1, b1, h2b);
    // layer 2: aggregate AFTER the neighbor GEMM (agg is linear): hw2 = h2@Wn2 (47-wide)
    k_nmul<<<OUT_B, 512, 0, stream>>>(h2b, wN2, hw2b);
    k_agg48<<<AGG_B, 256, 0, stream>>>((const uint4*)hw2b, row_off, col, inv_deg,
                                       (float4*)agg2f);
    k_out2<<<OUT_B, 512, 0, stream>>>(h2b, agg2f, wS2, b2, out);
}

// Round 12
// 325.680 us; speedup vs baseline: 1.5478x; 1.0256x over previous
//
#include <hip/hip_runtime.h>
#include <hip/hip_bf16.h>

#define NN 100000
#define NE 1600000
#define F 128
#define NCLS 47

#define NPB 256        // nodes per bucket (d >> 8)
#define BUCKETS 391    // ceil(NN / NPB)
#define ABLK 512       // phase-A blocks
#define ACHUNK (NE / ABLK)  // 3125 edges per A-block

typedef __attribute__((ext_vector_type(8))) short short8;
typedef __attribute__((ext_vector_type(8))) unsigned short u16x8;
typedef __attribute__((ext_vector_type(4))) float f32x4;

#define MFMA16(A, B, C) __builtin_amdgcn_mfma_f32_16x16x32_bf16(A, B, C, 0, 0, 0)

__device__ __forceinline__ unsigned short b16(float f) {
    unsigned int u = __builtin_bit_cast(unsigned int, f);
    unsigned int r = u + 0x7FFFu + ((u >> 16) & 1u);  // RTN-even
    return (unsigned short)(r >> 16);
}
__device__ __forceinline__ float bflo(unsigned int u) { return __builtin_bit_cast(float, u << 16); }
__device__ __forceinline__ float bfhi(unsigned int u) { return __builtin_bit_cast(float, u & 0xFFFF0000u); }

// ---------- CSR build, phase A: bucket the edges ----------
__global__ void __launch_bounds__(256) k_bhist(const int* __restrict__ dst,
                                               int* __restrict__ bucket_cnt) {
    __shared__ int hist[BUCKETS];
    const int t = threadIdx.x;
    for (int i = t; i < BUCKETS; i += 256) hist[i] = 0;
    __syncthreads();
    const int e0 = blockIdx.x * ACHUNK;
    for (int i = t; i < ACHUNK; i += 256) atomicAdd(&hist[dst[e0 + i] >> 8], 1);
    __syncthreads();
    for (int i = t; i < BUCKETS; i += 256)
        if (hist[i]) atomicAdd(&bucket_cnt[i], hist[i]);
}

__global__ void k_bscan(const int* __restrict__ bucket_cnt, int* __restrict__ bucket_off,
                        int* __restrict__ cursor) {
    const int lane = threadIdx.x & 63;
    int run = 0;
#pragma unroll
    for (int c = 0; c < 7; c++) {
        int idx = c * 64 + lane;
        int v = (idx < BUCKETS) ? bucket_cnt[idx] : 0;
        int s = v;
#pragma unroll
        for (int off = 1; off < 64; off <<= 1) {
            int n = __shfl_up(s, off);
            if (lane >= off) s += n;
        }
        int excl = run + s - v;
        if (idx <= BUCKETS) {
            bucket_off[idx] = excl;
            cursor[idx] = excl;
        }
        run += __shfl(s, 63);
    }
}

__global__ void __launch_bounds__(256) k_bscatter(const int* __restrict__ src,
                                                  const int* __restrict__ dst,
                                                  int* __restrict__ cursor,
                                                  int2* __restrict__ ebuf) {
    __shared__ int hist[BUCKETS];
    __shared__ int base[BUCKETS];
    __shared__ int rank[BUCKETS];
    const int t = threadIdx.x;
    for (int i = t; i < BUCKETS; i += 256) {
        hist[i] = 0;
        rank[i] = 0;
    }
    __syncthreads();
    const int e0 = blockIdx.x * ACHUNK;
    for (int i = t; i < ACHUNK; i += 256) atomicAdd(&hist[dst[e0 + i] >> 8], 1);
    __syncthreads();
    for (int i = t; i < BUCKETS; i += 256) {
        int h = hist[i];
        base[i] = h ? atomicAdd(&cursor[i], h) : 0;
    }
    __syncthreads();
    for (int i = t; i < ACHUNK; i += 256) {
        int s = src[e0 + i];
        int d = dst[e0 + i];
        int b = d >> 8;
        int r = atomicAdd(&rank[b], 1);
        ebuf[base[b] + r] = make_int2(s, d);
    }
}

// ---------- CSR build, phase B (fused): per-bucket histogram -> scan -> row_off/inv_deg -> col ----------
__global__ void __launch_bounds__(256) k_bcsr(const int2* __restrict__ ebuf,
                                              const int* __restrict__ bucket_off,
                                              int* __restrict__ row_off,
                                              float* __restrict__ inv_deg,
                                              int* __restrict__ col) {
    __shared__ int cnt[NPB];   // histogram, then cursor
    __shared__ int ro[NPB];
    __shared__ int wsum[4];
    const int t = threadIdx.x, lane = t & 63, wid = t >> 6;
    cnt[t] = 0;
    __syncthreads();
    const int e0 = bucket_off[blockIdx.x], e1 = bucket_off[blockIdx.x + 1];
    for (int i = e0 + t; i < e1; i += 256) atomicAdd(&cnt[ebuf[i].y & 255], 1);
    __syncthreads();
    int v = cnt[t];
    int run = v;
#pragma unroll
    for (int off = 1; off < 64; off <<= 1) {
        int n = __shfl_up(run, off);
        if (lane >= off) run += n;
    }
    if (lane == 63) wsum[wid] = run;
    __syncthreads();
    int woff = e0;  // bucket's global edge base
#pragma unroll
    for (int wv = 0; wv < 4; wv++)
        if (wv < wid) woff += wsum[wv];
    int excl = woff + run - v;
    int node = (blockIdx.x << 8) + t;
    if (node < NN) {
        row_off[node] = excl;
        inv_deg[node] = 1.0f / fmaxf((float)v, 1.0f);
    }
    if (blockIdx.x == BUCKETS - 1 && t == 0) row_off[NN] = NE;
    ro[t] = excl;
    cnt[t] = 0;  // reuse as cursor
    __syncthreads();
    for (int i = e0 + t; i < e1; i += 256) {
        int2 e = ebuf[i];
        int d = e.y & 255;
        int p = atomicAdd(&cnt[d], 1);
        col[ro[d] + p] = e.x;
    }
}

// ---------- fp32 -> bf16 convert (x) ----------
__global__ void k_cvt(const float* __restrict__ x, unsigned short* __restrict__ xb) {
    int t = blockIdx.x * blockDim.x + threadIdx.x;
    if (t >= NN * F / 8) return;
    const float4* x4 = (const float4*)x;
    float4 a = x4[t * 2], b = x4[t * 2 + 1];
    u16x8 o;
    o[0] = b16(a.x); o[1] = b16(a.y); o[2] = b16(a.z); o[3] = b16(a.w);
    o[4] = b16(b.x); o[5] = b16(b.y); o[6] = b16(b.z); o[7] = b16(b.w);
    ((u16x8*)xb)[t] = o;
}

// ---------- zero pad row NN of the gather tables ----------
__global__ void k_zpad(unsigned short* __restrict__ xb, unsigned short* __restrict__ h1b,
                       unsigned short* __restrict__ hw2b) {
    int t = threadIdx.x;  // 128 threads
    xb[(size_t)NN * F + t] = 0;
    h1b[(size_t)NN * F + t] = 0;
    if (t < 64) hw2b[(size_t)NN * 64 + t] = 0;
}

// ---------- pack weights into MFMA-fragment-linear bf16 ----------
__global__ void k_pack_all(const float* __restrict__ Ws0, const float* __restrict__ Wn0,
                           const float* __restrict__ Ws1, const float* __restrict__ Wn1,
                           const float* __restrict__ Ws2, const float* __restrict__ Wn2,
                           unsigned short* __restrict__ wp) {
    int idx = blockIdx.x * blockDim.x + threadIdx.x;
    if (idx >= 77824) return;
    const float* W;
    int base, ncols;
    if (idx < 65536) {
        int m = idx >> 14;
        W = (m == 0) ? Ws0 : (m == 1) ? Wn0 : (m == 2) ? Ws1 : Wn1;
        base = m << 14;
        ncols = 128;
    } else {
        int m = (idx - 65536) / 6144;
        W = m ? Wn2 : Ws2;
        base = 65536 + m * 6144;
        ncols = NCLS;
    }
    int li = idx - base;
    int nt = li >> 11;
    int r = li & 2047;
    int kk = r >> 9;
    int r2 = r & 511;
    int lane = r2 >> 3;
    int j = r2 & 7;
    int k = kk * 32 + ((lane >> 4) << 3) + j;
    int n = nt * 16 + (lane & 15);
    float v = (n < ncols) ? W[k * ncols + n] : 0.f;
    wp[idx] = b16(v);
}

// ---------- mean aggregation (128-wide): 4 rows/instr, zero-row padding (no masks) ----------
__global__ void __launch_bounds__(256) k_aggb(const uint4* __restrict__ h4,
                                              const int* __restrict__ row_off,
                                              const int* __restrict__ col,
                                              const float* __restrict__ inv_deg,
                                              uint4* __restrict__ a4) {
    int node = (blockIdx.x * blockDim.x + threadIdx.x) >> 6;
    int lane = threadIdx.x & 63;
    if (node >= NN) return;
    int b = row_off[node], e = row_off[node + 1];
    int deg = e - b;
    const int g = lane >> 4, fl = lane & 15;
    float acc[8];
#pragma unroll
    for (int i = 0; i < 8; i++) acc[i] = 0.f;
    for (int base = 0; base < deg; base += 64) {
        int cnt = deg - base;
        if (cnt > 64) cnt = 64;
        int myc = col[b + base + (lane < cnt ? lane : 0)];
        for (int jj = 0; jj < cnt; jj += 16) {
            uint4 u[4];
#pragma unroll
            for (int k2 = 0; k2 < 4; k2++) {
                int r = jj + k2 * 4 + g;
                int c = __shfl(myc, r);
                c = (r < cnt) ? c : NN;  // zero row
                u[k2] = h4[(size_t)(unsigned)c * 16u + fl];
            }
#pragma unroll
            for (int k2 = 0; k2 < 4; k2++) {
                uint4 v = u[k2];
                acc[0] += bflo(v.x); acc[1] += bfhi(v.x);
                acc[2] += bflo(v.y); acc[3] += bfhi(v.y);
                acc[4] += bflo(v.z); acc[5] += bfhi(v.z);
                acc[6] += bflo(v.w); acc[7] += bfhi(v.w);
            }
        }
    }
#pragma unroll
    for (int i = 0; i < 8; i++) {
        acc[i] += __shfl_xor(acc[i], 16);
        acc[i] += __shfl_xor(acc[i], 32);
    }
    if (g == 0) {
        float s = inv_deg[node];
        uint4 o;
        o.x = (unsigned)b16(acc[0] * s) | ((unsigned)b16(acc[1] * s) << 16);
        o.y = (unsigned)b16(acc[2] * s) | ((unsigned)b16(acc[3] * s) << 16);
        o.z = (unsigned)b16(acc[4] * s) | ((unsigned)b16(acc[5] * s) << 16);
        o.w = (unsigned)b16(acc[6] * s) | ((unsigned)b16(acc[7] * s) << 16);
        a4[(size_t)node * 16 + fl] = o;
    }
}

// ---------- mean aggregation (64-wide hw2 rows): 8 rows/instr, zero-row padding ----------
__global__ void __launch_bounds__(256) k_agg48(const uint4* __restrict__ hw4,
                                               const int* __restrict__ row_off,
                                               const int* __restrict__ col,
                                               const float* __restrict__ inv_deg,
                                               float4* __restrict__ aggf4) {
    int node = (blockIdx.x * blockDim.x + threadIdx.x) >> 6;
    int lane = threadIdx.x & 63;
    if (node >= NN) return;
    int b = row_off[node], e = row_off[node + 1];
    int deg = e - b;
    const int g = lane >> 3, fl = lane & 7;
    float acc[8];
#pragma unroll
    for (int i = 0; i < 8; i++) acc[i] = 0.f;
    for (int base = 0; base < deg; base += 64) {
        int cnt = deg - base;
        if (cnt > 64) cnt = 64;
        int myc = col[b + base + (lane < cnt ? lane : 0)];
        for (int jj = 0; jj < cnt; jj += 16) {
            uint4 u[2];
#pragma unroll
            for (int k2 = 0; k2 < 2; k2++) {
                int r = jj + k2 * 8 + g;
                int c = __shfl(myc, r);
                c = (r < cnt) ? c : NN;  // zero row
                u[k2] = hw4[(size_t)(unsigned)c * 8u + fl];
            }
#pragma unroll
            for (int k2 = 0; k2 < 2; k2++) {
                uint4 v = u[k2];
                acc[0] += bflo(v.x); acc[1] += bfhi(v.x);
                acc[2] += bflo(v.y); acc[3] += bfhi(v.y);
                acc[4] += bflo(v.z); acc[5] += bfhi(v.z);
                acc[6] += bflo(v.w); acc[7] += bfhi(v.w);
            }
        }
    }
#pragma unroll
    for (int i = 0; i < 8; i++) {
        acc[i] += __shfl_xor(acc[i], 8);
        acc[i] += __shfl_xor(acc[i], 16);
        acc[i] += __shfl_xor(acc[i], 32);
    }
    if (lane < 8) {
        float s = inv_deg[node];
        float4 o0 = make_float4(acc[0] * s, acc[1] * s, acc[2] * s, acc[3] * s);
        float4 o1 = make_float4(acc[4] * s, acc[5] * s, acc[6] * s, acc[7] * s);
        aggf4[(size_t)node * 16 + fl * 2] = o0;
        aggf4[(size_t)node * 16 + fl * 2 + 1] = o1;
    }
}

// ---------- fused dual-GEMM layer via MFMA ----------
template <bool RELU>
__global__ void __launch_bounds__(256) k_layer(const unsigned short* __restrict__ hb,
                                               const unsigned short* __restrict__ ab,
                                               const unsigned short* __restrict__ wps,
                                               const unsigned short* __restrict__ wpn,
                                               const float* __restrict__ bias,
                                               unsigned short* __restrict__ outb) {
    const int wid = threadIdx.x >> 6, lane = threadIdx.x & 63;
    const int tile0 = blockIdx.x * 64;
    const short8* ws8 = (const short8*)wps;
    const short8* wn8 = (const short8*)wpn;
    short8 wf[2][2][4];
#pragma unroll
    for (int t = 0; t < 2; t++) {
        int nt = 2 * wid + t;
#pragma unroll
        for (int kk = 0; kk < 4; kk++) {
            wf[0][t][kk] = ws8[(nt * 4 + kk) * 64 + lane];
            wf[1][t][kk] = wn8[(nt * 4 + kk) * 64 + lane];
        }
    }
    const int rb = lane & 15, kq = lane >> 4;
    float bv[2];
#pragma unroll
    for (int t = 0; t < 2; t++) bv[t] = bias[(2 * wid + t) * 16 + rb];
    const short8* h8 = (const short8*)hb;
    const short8* a8 = (const short8*)ab;
    f32x4 zero = {0.f, 0.f, 0.f, 0.f};
    f32x4 acc[4][2];
#pragma unroll
    for (int m = 0; m < 4; m++)
#pragma unroll
        for (int t = 0; t < 2; t++) acc[m][t] = zero;
#pragma unroll
    for (int kk = 0; kk < 4; kk++) {
#pragma unroll
        for (int m = 0; m < 4; m++) {
            int row = tile0 + m * 16 + rb;
            int rc = row < NN ? row : NN - 1;
            int idx = rc * 16 + kk * 4 + kq;
            short8 af = h8[idx];
            short8 gf = a8[idx];
            acc[m][0] = MFMA16(af, wf[0][0][kk], acc[m][0]);
            acc[m][1] = MFMA16(af, wf[0][1][kk], acc[m][1]);
            acc[m][0] = MFMA16(gf, wf[1][0][kk], acc[m][0]);
            acc[m][1] = MFMA16(gf, wf[1][1][kk], acc[m][1]);
        }
    }
#pragma unroll
    for (int m = 0; m < 4; m++) {
#pragma unroll
        for (int reg = 0; reg < 4; reg++) {
            int row = tile0 + m * 16 + kq * 4 + reg;
            if (row < NN) {
#pragma unroll
                for (int t = 0; t < 2; t++) {
                    float v = acc[m][t][reg] + bv[t];
                    if (RELU) v = fmaxf(v, 0.f);
                    outb[(size_t)row * F + (2 * wid + t) * 16 + rb] = b16(v);
                }
            }
        }
    }
}

// ---------- hw2 = h2 @ Wn2 (bf16 out, [NN+1][64], cols 48-63 unwritten/unused) ----------
__global__ void __launch_bounds__(512) k_nmul(const unsigned short* __restrict__ hb,
                                              const unsigned short* __restrict__ wpn,
                                              unsigned short* __restrict__ hw) {
    const int wid = threadIdx.x >> 6, lane = threadIdx.x & 63;
    const int R0 = blockIdx.x * 128 + wid * 16;
    const short8* wn8 = (const short8*)wpn;
    short8 wf[3][4];
#pragma unroll
    for (int nt = 0; nt < 3; nt++)
#pragma unroll
        for (int kk = 0; kk < 4; kk++) wf[nt][kk] = wn8[(nt * 4 + kk) * 64 + lane];
    const int rb = lane & 15, kq = lane >> 4;
    const short8* h8 = (const short8*)hb;
    f32x4 zero = {0.f, 0.f, 0.f, 0.f};
    f32x4 acc[3] = {zero, zero, zero};
    int rowr = R0 + rb;
    int rc = rowr < NN ? rowr : NN - 1;
#pragma unroll
    for (int kk = 0; kk < 4; kk++) {
        short8 af = h8[rc * 16 + kk * 4 + kq];
#pragma unroll
        for (int nt = 0; nt < 3; nt++) acc[nt] = MFMA16(af, wf[nt][kk], acc[nt]);
    }
#pragma unroll
    for (int reg = 0; reg < 4; reg++) {
        int row = R0 + kq * 4 + reg;
        if (row < NN) {
#pragma unroll
            for (int nt = 0; nt < 3; nt++)
                hw[(size_t)row * 64 + nt * 16 + rb] = b16(acc[nt][reg]);
        }
    }
}

// ---------- final layer: self-GEMM + aggregated hw + bias + log_softmax ----------
__global__ void __launch_bounds__(512) k_out2(const unsigned short* __restrict__ hb,
                                              const float* __restrict__ aggf,
                                              const unsigned short* __restrict__ wps,
                                              const float* __restrict__ bias,
                                              float* __restrict__ out) {
    const int wid = threadIdx.x >> 6, lane = threadIdx.x & 63;
    const int R0 = blockIdx.x * 128 + wid * 16;
    const short8* ws8 = (const short8*)wps;
    short8 wf[3][4];
#pragma unroll
    for (int nt = 0; nt < 3; nt++)
#pragma unroll
        for (int kk = 0; kk < 4; kk++) wf[nt][kk] = ws8[(nt * 4 + kk) * 64 + lane];
    const int rb = lane & 15, kq = lane >> 4;
    float bv[3];
    bool valid[3];
#pragma unroll
    for (int nt = 0; nt < 3; nt++) {
        int c = nt * 16 + rb;
        valid[nt] = c < NCLS;
        bv[nt] = valid[nt] ? bias[c] : 0.f;
    }
    const short8* h8 = (const short8*)hb;
    f32x4 zero = {0.f, 0.f, 0.f, 0.f};
    f32x4 acc[3] = {zero, zero, zero};
    int rowr = R0 + rb;
    int rc = rowr < NN ? rowr : NN - 1;
#pragma unroll
    for (int kk = 0; kk < 4; kk++) {
        short8 af = h8[rc * 16 + kk * 4 + kq];
#pragma unroll
        for (int nt = 0; nt < 3; nt++) acc[nt] = MFMA16(af, wf[nt][kk], acc[nt]);
    }
#pragma unroll
    for (int reg = 0; reg < 4; reg++) {
        int row = R0 + kq * 4 + reg;
        int rc2 = row < NN ? row : NN - 1;
        float v[3];
        float mx = -1e30f;
#pragma unroll
        for (int nt = 0; nt < 3; nt++) {
            float av = aggf[(size_t)rc2 * 64 + nt * 16 + rb];
            v[nt] = acc[nt][reg] + av + bv[nt];
            if (valid[nt]) mx = fmaxf(mx, v[nt]);
        }
        for (int off = 1; off < 16; off <<= 1) mx = fmaxf(mx, __shfl_xor(mx, off));
        float s = 0.f;
#pragma unroll
        for (int nt = 0; nt < 3; nt++)
            if (valid[nt]) s += expf(v[nt] - mx);
        for (int off = 1; off < 16; off <<= 1) s += __shfl_xor(s, off);
        float L = mx + logf(s);
        if (row < NN) {
#pragma unroll
            for (int nt = 0; nt < 3; nt++)
                if (valid[nt]) out[(size_t)row * NCLS + nt * 16 + rb] = v[nt] - L;
        }
    }
}

extern "C" void kernel_launch(void* const* d_in, const int* in_sizes, int n_in,
                              void* d_out, int out_size, void* d_ws, size_t ws_size,
                              hipStream_t stream) {
    (void)in_sizes; (void)n_in; (void)out_size; (void)ws_size;
    const float* x = (const float*)d_in[0];
    const int* src = (const int*)d_in[1];
    const int* dst = (const int*)d_in[2];
    const float* Ws0 = (const float*)d_in[3];
    const float* Wn0 = (const float*)d_in[4];
    const float* b0 = (const float*)d_in[5];
    const float* Ws1 = (const float*)d_in[6];
    const float* Wn1 = (const float*)d_in[7];
    const float* b1 = (const float*)d_in[8];
    const float* Ws2 = (const float*)d_in[9];
    const float* Wn2 = (const float*)d_in[10];
    const float* b2 = (const float*)d_in[11];
    float* out = (float*)d_out;

    char* w = (char*)d_ws;
    size_t off = 0;
    auto alloc = [&](size_t bytes) -> char* {
        char* p = w + off;
        off = (off + bytes + 255) & ~(size_t)255;
        return p;
    };
    int* row_off = (int*)alloc((size_t)(NN + 1) * 4);
    int* col = (int*)alloc((size_t)NE * 4);
    float* inv_deg = (float*)alloc((size_t)NN * 4);
    int* bucket_cnt = (int*)alloc((size_t)(BUCKETS + 1) * 4);
    int* bucket_off = (int*)alloc((size_t)(BUCKETS + 1) * 4);
    int* bcursor = (int*)alloc((size_t)(BUCKETS + 1) * 4);
    int2* ebuf = (int2*)alloc((size_t)NE * 8 + 256);  // reused as hw2 [(NN+1)][64] bf16
    unsigned short* xb = (unsigned short*)alloc((size_t)(NN + 1) * F * 2);
    unsigned short* aggb = (unsigned short*)alloc((size_t)NN * F * 2);  // reused as agg2f
    unsigned short* h1b = (unsigned short*)alloc((size_t)(NN + 1) * F * 2);
    unsigned short* h2b = (unsigned short*)alloc((size_t)NN * F * 2);
    unsigned short* wp = (unsigned short*)alloc((size_t)77824 * 2);

    unsigned short* hw2b = (unsigned short*)ebuf;  // [(NN+1)][64] bf16 = 12.80 MB
    float* agg2f = (float*)aggb;                   // [NN][64] fp32 = 25.6 MB

    hipMemsetAsync(bucket_cnt, 0, (size_t)(BUCKETS + 1) * 4, stream);

    // CSR build
    k_bhist<<<ABLK, 256, 0, stream>>>(dst, bucket_cnt);
    k_bscan<<<1, 64, 0, stream>>>(bucket_cnt, bucket_off, bcursor);
    k_bscatter<<<ABLK, 256, 0, stream>>>(src, dst, bcursor, ebuf);
    k_bcsr<<<BUCKETS, 256, 0, stream>>>(ebuf, bucket_off, row_off, inv_deg, col);

    k_cvt<<<(NN * F / 8 + 255) / 256, 256, 0, stream>>>(x, xb);
    k_pack_all<<<(77824 + 255) / 256, 256, 0, stream>>>(Ws0, Wn0, Ws1, Wn1, Ws2, Wn2, wp);

    unsigned short* wS0 = wp;
    unsigned short* wN0 = wp + 16384;
    unsigned short* wS1 = wp + 32768;
    unsigned short* wN1 = wp + 49152;
    unsigned short* wS2 = wp + 65536;
    unsigned short* wN2 = wp + 71680;

    const int AGG_B = NN * 64 / 256;            // 25000 (wave per node)
    const int LYR_B = (NN + 63) / 64;           // 1563
    const int OUT_B = (NN + 127) / 128;         // 782

    k_zpad<<<1, 128, 0, stream>>>(xb, h1b, hw2b);

    // layer 0
    k_aggb<<<AGG_B, 256, 0, stream>>>((const uint4*)xb, row_off, col, inv_deg, (uint4*)aggb);
    k_layer<true><<<LYR_B, 256, 0, stream>>>(xb, aggb, wS0, wN0, b0, h1b);
    // layer 1
    k_aggb<<<AGG_B, 256, 0, stream>>>((const uint4*)h1b, row_off, col, inv_deg, (uint4*)aggb);
    k_layer<true><<<LYR_B, 256, 0, stream>>>(h1b, aggb, wS1, wN1, b1, h2b);
    // layer 2: aggregate AFTER the neighbor GEMM (agg is linear): hw2 = h2@Wn2 (47-wide)
    k_nmul<<<OUT_B, 512, 0, stream>>>(h2b, wN2, hw2b);
    k_agg48<<<AGG_B, 256, 0, stream>>>((const uint4*)hw2b, row_off, col, inv_deg,
                                       (float4*)agg2f);
    k_out2<<<OUT_B, 512, 0, stream>>>(h2b, agg2f, wS2, b2, out);
}